// Round 11
// baseline (337.800 us; speedup 1.0000x reference)
//
#include <hip/hip_runtime.h>

typedef _Float16 half8 __attribute__((ext_vector_type(8)));
typedef _Float16 half4 __attribute__((ext_vector_type(4)));
typedef _Float16 half2v __attribute__((ext_vector_type(2)));
typedef float floatx4 __attribute__((ext_vector_type(4)));

// Problem constants (fixed by reference)
constexpr int NN = 100000;   // nodes
constexpr int EE = 1600000;  // edges
constexpr int NBK = 391;     // partition buckets: ceil(100000/256), dst>>8
constexpr int CHUNK = 3125;  // edges per sort block (512 sort blocks)
constexpr int CAPB = 6144;   // per-bucket slab capacity (mean 4092, 32 sigma)
constexpr int LCAP = 4608;   // k_part2 LDS record capacity (mean + 8 sigma)
constexpr int NDCAP = 48;    // per-node LDS edge cap (mean deg 16; mult of 16)

// ---- fused pass A + prep ----
// Blocks [0,512): block-local counting sort into coarse buckets (dst>>8),
//   self-allocating slabs part[bk*CAPB...], gcur[bk] counts (zeroed by
//   hipMemsetAsync before launch).
// Blocks [512,3637): h fp32->fp16 conversion. Blocks [3637,3733): bbt.
// R7 lesson: no global-atomic hist/place (1.6M random atomics ~100+ us).
// R9 lesson: 1024 sort blocks regress (per-block overhead doubles).
// record: x = (dst<<15) | (src>>2); y = (src&3) | (et<<2) | (norm_fp16<<5)
__global__ __launch_bounds__(512) void k_partprep(const int* __restrict__ dst,
                                                  const int* __restrict__ src,
                                                  const int* __restrict__ etype,
                                                  const float* __restrict__ norm,
                                                  int* __restrict__ gcur,
                                                  int2* __restrict__ part,
                                                  const float* __restrict__ h,
                                                  _Float16* __restrict__ hh,
                                                  const float* __restrict__ b0,
                                                  const float* __restrict__ b1,
                                                  const float* __restrict__ b2,
                                                  _Float16* __restrict__ bbt) {
  __shared__ int2 ldata[CHUNK];             // 25000 B
  __shared__ unsigned short lbkt[CHUNK];    // 6250 B
  __shared__ int lhist[NBK], lbase[NBK + 1], lcur[NBK], gbase[NBK];
  __shared__ int swsum[8];
  const int tid = threadIdx.x;
  const int bx = blockIdx.x;

  if (bx >= 512) {
    if (bx < 3637) {
      const int i = (bx - 512) * 512 + tid;
      const float4 v = *(const float4*)&h[(size_t)i * 4];
      half4 o = {(_Float16)v.x, (_Float16)v.y, (_Float16)v.z, (_Float16)v.w};
      *(half4*)&hh[(size_t)i * 4] = o;
    } else {
      const int L = (bx - 3637) * 512 + tid;
      const int g = L >> 14;          // layer 0..2
      const int idx = L & 16383;
      const float* bases = (g == 0) ? b0 : (g == 1) ? b1 : b2;
      const int o = idx >> 8, k = idx & 255;
      const int b = k >> 6, i = k & 63;
      bbt[g * 16384 + idx] = (_Float16)bases[b * 4096 + i * 64 + o];
    }
    return;
  }

  // ---- sort branch ----
  const int e0 = bx * CHUNK;

  if (tid < NBK) lhist[tid] = 0;
  __syncthreads();
  for (int i = tid; i < CHUNK; i += 512)
    atomicAdd(&lhist[dst[e0 + i] >> 8], 1);
  __syncthreads();
  {
    const int v = (tid < NBK) ? lhist[tid] : 0;
    int incl = v;
    for (int d = 1; d < 64; d <<= 1) {
      const int t = __shfl_up(incl, d);
      if ((tid & 63) >= d) incl += t;
    }
    if ((tid & 63) == 63) swsum[tid >> 6] = incl;
    __syncthreads();
    int pre = 0;
    for (int w = 0; w < (tid >> 6); ++w) pre += swsum[w];
    const int excl = pre + incl - v;
    if (tid < NBK) {
      lbase[tid] = excl;
      lcur[tid] = 0;
      gbase[tid] = tid * CAPB + atomicAdd(&gcur[tid], v);
    }
    if (tid == 0) lbase[NBK] = CHUNK;
  }
  __syncthreads();
  for (int i = tid; i < CHUNK; i += 512) {
    const int e = e0 + i;
    const int d = dst[e], s = src[e], et = etype[e];
    const _Float16 nh = (_Float16)norm[e];
    const unsigned short n16 = __builtin_bit_cast(unsigned short, nh);
    const int bk = d >> 8;
    const int pos = lbase[bk] + atomicAdd(&lcur[bk], 1);
    ldata[pos] = make_int2((d << 15) | (s >> 2), (s & 3) | (et << 2) | ((int)n16 << 5));
    lbkt[pos] = (unsigned short)bk;
  }
  __syncthreads();
  for (int i = tid; i < CHUNK; i += 512) {
    const int bk = (int)lbkt[i];
    part[gbase[bk] + (i - lbase[bk])] = ldata[i];
  }
}

// ---- pass B: per-bucket node histogram + scan -> off[]; exact placement ----
// 391 blocks x 1024 threads. Single-pass: records staged into LDS during
// the histogram read; placement reads LDS (wave-uniform two-pass fallback
// if a bucket exceeds LCAP = mean + 8 sigma).
// em record: x = (d&15)<<23 | et<<20 | src, y = norm fp32 bits.
__global__ __launch_bounds__(1024) void k_part2(const int* __restrict__ gcur,
                                                const int2* __restrict__ part,
                                                int* __restrict__ off,
                                                int2* __restrict__ em) {
  __shared__ int2 lrec[LCAP];   // 36864 B
  __shared__ int hcnt[256];
  __shared__ int wred[16];
  __shared__ int swsum[4];
  const int tid = threadIdx.x;
  const int bk = blockIdx.x;
  const int nb0 = bk << 8;
  const int2* __restrict__ pp = part + (size_t)bk * CAPB;

  {
    int pv = (tid < bk) ? gcur[tid] : 0;
    for (int d = 32; d > 0; d >>= 1) pv += __shfl_down(pv, d);
    if ((tid & 63) == 0) wred[tid >> 6] = pv;
  }
  if (tid < 256) hcnt[tid] = 0;
  __syncthreads();
  int base = 0;
#pragma unroll
  for (int w = 0; w < 16; ++w) base += wred[w];
  const int cntb = gcur[bk];
  const bool uselds = (cntb <= LCAP);

  if (uselds) {
    for (int i = tid; i < cntb; i += 1024) {
      const int2 r = pp[i];
      lrec[i] = r;
      atomicAdd(&hcnt[(((unsigned)r.x) >> 15) & 255], 1);
    }
  } else {
    for (int i = tid; i < cntb; i += 1024)
      atomicAdd(&hcnt[(((unsigned)pp[i].x) >> 15) & 255], 1);
  }
  __syncthreads();
  const int v = (tid < 256) ? hcnt[tid] : 0;
  int incl = v;
  for (int d = 1; d < 64; d <<= 1) {
    const int t = __shfl_up(incl, d);
    if ((tid & 63) >= d) incl += t;
  }
  if (tid < 256 && (tid & 63) == 63) swsum[tid >> 6] = incl;
  __syncthreads();
  if (tid < 256) {
    int pre = 0;
    for (int w = 0; w < (tid >> 6); ++w) pre += swsum[w];
    const int excl = pre + incl - v;  // bucket-local exclusive offset
    const int n = nb0 + tid;
    if (n < NN) off[n] = base + excl;
    hcnt[tid] = excl;  // cursors
  }
  if (bk == NBK - 1 && tid == 0) off[NN] = EE;
  __syncthreads();
  for (int i = tid; i < cntb; i += 1024) {
    const int2 r = uselds ? lrec[i] : pp[i];
    const int d = ((unsigned)r.x) >> 15;
    const int s = ((r.x & 0x7FFF) << 2) | (r.y & 3);
    const int et = (r.y >> 2) & 7;
    const unsigned short n16 = (unsigned short)((r.y >> 5) & 0xFFFF);
    const float nf = (float)__builtin_bit_cast(_Float16, n16);
    const int pos = atomicAdd(&hcnt[d & 255], 1);
    em[base + pos] = make_int2(((d & 15) << 23) | (et << 20) | s, __float_as_int(nf));
  }
}

// ---------------- fused layer: gather + basis-GEMM (MFMA) + optional dec ----
// R9-proven core (54 us, VGPR 32, no scratch; cvt_pkrtz staging) with:
//  - tail-only LDS slot zeroing (zero [cnt, nbq*16) per node, not all 48)
//  - layer-3 fused decoder: after MFMA the block holds henc[16][64] in regs;
//    stash into Ash-as-fp32 (4352B <= 8448B, no extra LDS), then compute
//    rec[n] = b2 + sum_o relu(b1+henc@w1)*w2 in-block. Replaces k_dec
//    (saves the full 25.6MB henc re-read + a launch).
// NOTE (R3+R5): deeper gather pipelines get stack-demoted by hipcc ->
// 500+MB scratch traffic. Do not re-attempt deep SWP at HIP source level.
__global__ __launch_bounds__(256, 8) void k_layer(const _Float16* __restrict__ hh,
                                                  const int* __restrict__ off,
                                                  const int2* __restrict__ em,
                                                  const float* __restrict__ wcomp,
                                                  const _Float16* __restrict__ bbt,
                                                  _Float16* __restrict__ out16,
                                                  float* __restrict__ out32,
                                                  const float* __restrict__ dw1,
                                                  const float* __restrict__ db1,
                                                  const float* __restrict__ dw2,
                                                  const float* __restrict__ db2,
                                                  float* __restrict__ rec) {
  __shared__ _Float16 Ash[16 * 264];   // 8448 B (reused as fp32 [16][68] in dec)
  __shared__ int  ems_s[16 * NDCAP];   // 3072 B: src per slot
  __shared__ int2 ems_c[16 * NDCAP];   // 6144 B: coeff pairs {c0,c1},{c2,c3}
  __shared__ float4 wcs[8];
  __shared__ int offs[17];
  __shared__ int ovf;
  const int tid = threadIdx.x;
  const int lane = tid & 63;
  const int wv = tid >> 6;
  const int n0 = blockIdx.x * 16;

  if (tid < 17) offs[tid] = off[n0 + tid];
  if (tid == 0) ovf = 0;
  if (tid < 8) wcs[tid] = ((const float4*)wcomp)[tid];
  __syncthreads();  // offs ready

  // tail-only zeroing: slots [cnt, nbq*16) of node tid>>4 (disjoint from
  // staging's writes [0,cnt), both run between this pair of barriers)
  {
    const int n = tid >> 4, j = tid & 15;
    const int cnt = offs[n + 1] - offs[n];
    const int nb = (cnt > 0) ? ((cnt + 15) >> 4) : 1;
    const int sl = cnt + j;
    if (sl < nb * 16 && sl < NDCAP) {
      ems_s[n * NDCAP + sl] = 0;
      ems_c[n * NDCAP + sl] = make_int2(0, 0);
    }
  }

  const int e0 = offs[0];
  const int len = offs[16] - e0;
  for (int i = tid; i < len; i += 256) {
    const int g = e0 + i;
    const int2 r = em[g];
    const int lo = (r.x >> 23) & 15;
    const int rank = g - offs[lo];
    const int et = (r.x >> 20) & 7;
    const int s = r.x & 0xFFFFF;
    const float nf = __int_as_float(r.y);
    const float4 w = wcs[et];
    const int p01i = __builtin_bit_cast(int, __builtin_amdgcn_cvt_pkrtz(nf * w.x, nf * w.y));
    const int p23i = __builtin_bit_cast(int, __builtin_amdgcn_cvt_pkrtz(nf * w.z, nf * w.w));
    if (rank < NDCAP) {
      ems_s[lo * NDCAP + rank] = s;
      ems_c[lo * NDCAP + rank] = make_int2(p01i, p23i);
    } else ovf = 1;
  }
  __syncthreads();

#define LOADB(mm, bb, hv)                                                      \
  {                                                                            \
    const int4* sp4_ = (const int4*)&ems_s[(mm) * NDCAP + (bb) * 16 + eg * 8]; \
    const int4 sa_ = sp4_[0], sb_ = sp4_[1];                                   \
    hv[0] = hp[(unsigned)sa_.x * 32u + fl];                                    \
    hv[1] = hp[(unsigned)sa_.y * 32u + fl];                                    \
    hv[2] = hp[(unsigned)sa_.z * 32u + fl];                                    \
    hv[3] = hp[(unsigned)sa_.w * 32u + fl];                                    \
    hv[4] = hp[(unsigned)sb_.x * 32u + fl];                                    \
    hv[5] = hp[(unsigned)sb_.y * 32u + fl];                                    \
    hv[6] = hp[(unsigned)sb_.z * 32u + fl];                                    \
    hv[7] = hp[(unsigned)sb_.w * 32u + fl];                                    \
  }

#define FMAQ(mm, bb, hv, aq)                                                   \
  {                                                                            \
    const int4* cp4_ = (const int4*)&ems_c[(mm) * NDCAP + (bb) * 16 + eg * 8]; \
    _Pragma("unroll")                                                          \
    for (int k_ = 0; k_ < 4; ++k_) {                                           \
      const int4 c_ = cp4_[k_];                                                \
      const half2v pa01_ = __builtin_bit_cast(half2v, c_.x);                   \
      const half2v pa23_ = __builtin_bit_cast(half2v, c_.y);                   \
      const half2v pb01_ = __builtin_bit_cast(half2v, c_.z);                   \
      const half2v pb23_ = __builtin_bit_cast(half2v, c_.w);                   \
      aq[0] = aq[0] + hv[2 * k_] * __builtin_shufflevector(pa01_, pa01_, 0, 0);\
      aq[1] = aq[1] + hv[2 * k_] * __builtin_shufflevector(pa01_, pa01_, 1, 1);\
      aq[2] = aq[2] + hv[2 * k_] * __builtin_shufflevector(pa23_, pa23_, 0, 0);\
      aq[3] = aq[3] + hv[2 * k_] * __builtin_shufflevector(pa23_, pa23_, 1, 1);\
      aq[0] = aq[0] + hv[2 * k_ + 1] * __builtin_shufflevector(pb01_, pb01_, 0, 0);\
      aq[1] = aq[1] + hv[2 * k_ + 1] * __builtin_shufflevector(pb01_, pb01_, 1, 1);\
      aq[2] = aq[2] + hv[2 * k_ + 1] * __builtin_shufflevector(pb23_, pb23_, 0, 0);\
      aq[3] = aq[3] + hv[2 * k_ + 1] * __builtin_shufflevector(pb23_, pb23_, 1, 1);\
    }                                                                          \
  }

  if (!ovf) {
    // fast path: fp16 packed accumulation, zero-padded 16-slot batches,
    // depth-1 pipeline across the wave's 4 nodes (hvA/hvB double buffer).
    const int fl = lane & 31;   // feature pair index (feats 2fl, 2fl+1)
    const int eg = lane >> 5;   // edge group 0/1
    const half2v* __restrict__ hp = (const half2v*)hh;
    const int mb = wv * 4;
    const int oA = offs[mb], oB = offs[mb + 1], oC = offs[mb + 2],
              oD = offs[mb + 3], oE = offs[mb + 4];
    const int c0n = oB - oA, c1n = oC - oB, c2n = oD - oC, c3n = oE - oD;
    const int nb0_ = (c0n > 0) ? ((c0n + 15) >> 4) : 1;
    const int nb1_ = (c1n > 0) ? ((c1n + 15) >> 4) : 1;
    const int nb2_ = (c2n > 0) ? ((c2n + 15) >> 4) : 1;
    const int nb3_ = (c3n > 0) ? ((c3n + 15) >> 4) : 1;

    half2v acc[4][4];
#pragma unroll
    for (int q = 0; q < 4; ++q)
#pragma unroll
      for (int i = 0; i < 4; ++i) acc[q][i] = half2v{0, 0};

    half2v hvA[8], hvB[8];
    LOADB(mb, 0, hvA);
#pragma unroll
    for (int q = 0; q < 4; ++q) {
      const int m = mb + q;
      const int nbq = (q == 0) ? nb0_ : (q == 1) ? nb1_ : (q == 2) ? nb2_ : nb3_;
      if (q < 3) {
        if (q & 1) LOADB(m + 1, 0, hvA) else LOADB(m + 1, 0, hvB)
      }
      if (q & 1) FMAQ(m, 0, hvB, acc[q]) else FMAQ(m, 0, hvA, acc[q])
      for (int b = 1; b < nbq; ++b) {  // rare (deg > 16)
        if (q & 1) {
          LOADB(m, b, hvB) FMAQ(m, b, hvB, acc[q])
        } else {
          LOADB(m, b, hvA) FMAQ(m, b, hvA, acc[q])
        }
      }
    }
#pragma unroll
    for (int q = 0; q < 4; ++q) {
      const int m = mb + q;
#pragma unroll
      for (int i = 0; i < 4; ++i)
        acc[q][i] = acc[q][i] + __builtin_bit_cast(half2v,
            __shfl_xor(__builtin_bit_cast(int, acc[q][i]), 32));
      if (eg == 0) {
        _Float16* ar = &Ash[m * 264];
        *(half2v*)&ar[0 * 64 + 2 * fl] = acc[q][0];
        *(half2v*)&ar[1 * 64 + 2 * fl] = acc[q][1];
        *(half2v*)&ar[2 * 64 + 2 * fl] = acc[q][2];
        *(half2v*)&ar[3 * 64 + 2 * fl] = acc[q][3];
      }
    }
  } else {
    // slow path (deg > NDCAP): fp32 clamped batches straight from global em
    const _Float16* hl = hh + lane;
    for (int q = 0; q < 4; ++q) {
      const int m = wv * 4 + q;
      const int p0 = offs[m], p1 = offs[m + 1];
      float a0 = 0.f, a1 = 0.f, a2 = 0.f, a3 = 0.f;
      for (int p = p0; p < p1; p += 8) {
#pragma unroll
        for (int j = 0; j < 8; ++j) {
          const bool live = (p + j < p1);
          const int idx = live ? p + j : p1 - 1;
          const int2 mm = em[idx];
          const float hv = (float)hl[(size_t)(mm.x & 0xFFFFF) << 6];
          const float wn = live ? __int_as_float(mm.y) : 0.f;
          const float4 w = wcs[(mm.x >> 20) & 7];
          const float t = wn * hv;
          a0 = fmaf(t, w.x, a0); a1 = fmaf(t, w.y, a1);
          a2 = fmaf(t, w.z, a2); a3 = fmaf(t, w.w, a3);
        }
      }
      _Float16* ar = &Ash[m * 264];
      ar[lane]       = (_Float16)a0;
      ar[64 + lane]  = (_Float16)a1;
      ar[128 + lane] = (_Float16)a2;
      ar[192 + lane] = (_Float16)a3;
    }
  }
  __syncthreads();

  // MFMA: C[16 nodes][16 outs] per wave, outs = wv*16..+15, K = 256.
  const int col = lane & 15;
  const int quad = lane >> 4;
  const int obase = wv * 16 + col;
  const _Float16* ap = &Ash[col * 264 + quad * 8];
  const _Float16* bp = &bbt[(size_t)obase * 256 + quad * 8];
  floatx4 acc2 = {0.f, 0.f, 0.f, 0.f};
#pragma unroll
  for (int s = 0; s < 8; ++s) {
    const half8 af = *(const half8*)(ap + s * 32);
    const half8 bf = *(const half8*)(bp + s * 32);
    acc2 = __builtin_amdgcn_mfma_f32_16x16x32_f16(af, bf, acc2, 0, 0, 0);
  }
  if (out16) {
#pragma unroll
    for (int r = 0; r < 4; ++r) {
      const float c = fmaxf(acc2[r], 0.f);
      out16[(size_t)(n0 + quad * 4 + r) * 64 + obase] = (_Float16)c;
    }
  } else {
#pragma unroll
    for (int r = 0; r < 4; ++r) {
      out32[(size_t)(n0 + quad * 4 + r) * 64 + obase] = acc2[r];
    }
    // ---- fused decoder (layer 3 only; block-uniform branch) ----
    __syncthreads();  // all MFMA reads of Ash complete
    float* hsd = (float*)Ash;  // [16][68] fp32, 4352B <= 8448B
#pragma unroll
    for (int r = 0; r < 4; ++r)
      hsd[(quad * 4 + r) * 68 + obase] = acc2[r];
    __syncthreads();
    const int og = tid & 15;
    const int nl = tid >> 4;
    const float4 wv2 = *(const float4*)&dw2[og * 4];
    float4 dacc = *(const float4*)&db1[og * 4];
    const float* hr = &hsd[nl * 68];
#pragma unroll 8
    for (int i = 0; i < 64; ++i) {
      const float hv = hr[i];
      const float4 wv = *(const float4*)&dw1[i * 64 + og * 4];
      dacc.x = fmaf(hv, wv.x, dacc.x); dacc.y = fmaf(hv, wv.y, dacc.y);
      dacc.z = fmaf(hv, wv.z, dacc.z); dacc.w = fmaf(hv, wv.w, dacc.w);
    }
    dacc.x = fmaxf(dacc.x, 0.f); dacc.y = fmaxf(dacc.y, 0.f);
    dacc.z = fmaxf(dacc.z, 0.f); dacc.w = fmaxf(dacc.w, 0.f);
    float vdec = dacc.x * wv2.x + dacc.y * wv2.y + dacc.z * wv2.z + dacc.w * wv2.w;
    vdec += __shfl_xor(vdec, 1); vdec += __shfl_xor(vdec, 2);
    vdec += __shfl_xor(vdec, 4); vdec += __shfl_xor(vdec, 8);
    if (og == 0) rec[n0 + nl] = vdec + db2[0];
  }
#undef LOADB
#undef FMAQ
}

// ---------------- launch ----------------

extern "C" void kernel_launch(void* const* d_in, const int* in_sizes, int n_in,
                              void* d_out, int out_size, void* d_ws, size_t ws_size,
                              hipStream_t stream) {
  const float* h     = (const float*)d_in[0];
  const int*   src   = (const int*)d_in[1];
  const int*   dst   = (const int*)d_in[2];
  const int*   etype = (const int*)d_in[3];
  const float* norm  = (const float*)d_in[4];
  const float* bases[3] = {(const float*)d_in[5], (const float*)d_in[7], (const float*)d_in[9]};
  const float* wcomp[3] = {(const float*)d_in[6], (const float*)d_in[8], (const float*)d_in[10]};
  const float* dw1 = (const float*)d_in[11];
  const float* db1 = (const float*)d_in[12];
  const float* dw2 = (const float*)d_in[13];
  const float* db2 = (const float*)d_in[14];

  float* rec  = (float*)d_out;        // [N]
  float* henc = (float*)d_out + NN;   // [N,64] fp32 (layer-3 output)

  // workspace carve-up (16B-aligned)
  char* ws = (char*)d_ws;
  int*      off    = (int*)(ws + 0);              // (N+1) ints
  int*      gcur   = (int*)(ws + 400512);         // NBK bucket counters
  int2*     em     = (int2*)(ws + 402560);        // E records, dst-sorted
  _Float16* hh     = (_Float16*)(ws + 13202560);  // [N][64] fp16
  _Float16* h1f    = (_Float16*)(ws + 26002560);  // [N][64] fp16
  _Float16* h2f    = (_Float16*)(ws + 38802560);  // [N][64] fp16
  _Float16* bbt    = (_Float16*)(ws + 51602560);  // [3][64][256] fp16
  int2*     part   = (int2*)h1f;                  // NBK slabs x CAPB records
                                                  // (19.2 MB spanning h1f+h2f;
                                                  //  consumed in k_part2 before
                                                  //  layers write h1f/h2f)

  // ---- zero bucket counters (capture-safe async memset) ----
  hipMemsetAsync(gcur, 0, NBK * sizeof(int), stream);

  // ---- fused: dst-bucket sort (blocks 0-511) + fp16 prep (rest) ----
  k_partprep<<<3733, 512, 0, stream>>>(dst, src, etype, norm, gcur, part,
                                       h, hh, bases[0], bases[1], bases[2], bbt);
  k_part2<<<NBK, 1024, 0, stream>>>(gcur, part, off, em);

  // ---- fused layers (layer 3 also computes the decoder -> rec) ----
  k_layer<<<NN / 16, 256, 0, stream>>>(hh,  off, em, wcomp[0], bbt,         h1f, nullptr,
                                       nullptr, nullptr, nullptr, nullptr, nullptr);
  k_layer<<<NN / 16, 256, 0, stream>>>(h1f, off, em, wcomp[1], bbt + 16384, h2f, nullptr,
                                       nullptr, nullptr, nullptr, nullptr, nullptr);
  k_layer<<<NN / 16, 256, 0, stream>>>(h2f, off, em, wcomp[2], bbt + 32768, nullptr, henc,
                                       dw1, db1, dw2, db2, rec);
}

// Round 12
// 332.852 us; speedup vs baseline: 1.0149x; 1.0149x over previous
//
#include <hip/hip_runtime.h>

typedef _Float16 half8 __attribute__((ext_vector_type(8)));
typedef _Float16 half4 __attribute__((ext_vector_type(4)));
typedef _Float16 half2v __attribute__((ext_vector_type(2)));
typedef float floatx4 __attribute__((ext_vector_type(4)));

// Problem constants (fixed by reference)
constexpr int NN = 100000;   // nodes
constexpr int EE = 1600000;  // edges
constexpr int NBK = 391;     // partition buckets: ceil(100000/256), dst>>8
constexpr int CHUNK = 3125;  // edges per sort block (512 sort blocks)
constexpr int CAPB = 6144;   // per-bucket slab capacity (mean 4092, 32 sigma)
constexpr int LCAP = 4608;   // k_part2 LDS record capacity (mean + 8 sigma)
constexpr int NDCAP = 48;    // per-node LDS edge cap (mean deg 16; mult of 16)

// ---- fused pass A + prep ----
// Blocks [0,512): block-local counting sort into coarse buckets (dst>>8),
//   self-allocating slabs part[bk*CAPB...], gcur[bk] counts (zeroed by
//   hipMemsetAsync before launch).
// Blocks [512,3637): h fp32->fp16 conversion. Blocks [3637,3733): bbt.
// R7 lesson: no global-atomic hist/place (1.6M random atomics ~100+ us).
// R9 lesson: 1024 sort blocks regress (per-block overhead doubles).
// R11 lesson: dec-fusion into layer 3 costs +45us (epilogue serialization);
// keep k_dec standalone.
// record: x = (dst<<15) | (src>>2); y = (src&3) | (et<<2) | (norm_fp16<<5)
__global__ __launch_bounds__(512) void k_partprep(const int* __restrict__ dst,
                                                  const int* __restrict__ src,
                                                  const int* __restrict__ etype,
                                                  const float* __restrict__ norm,
                                                  int* __restrict__ gcur,
                                                  int2* __restrict__ part,
                                                  const float* __restrict__ h,
                                                  _Float16* __restrict__ hh,
                                                  const float* __restrict__ b0,
                                                  const float* __restrict__ b1,
                                                  const float* __restrict__ b2,
                                                  _Float16* __restrict__ bbt) {
  __shared__ int2 ldata[CHUNK];             // 25000 B
  __shared__ unsigned short lbkt[CHUNK];    // 6250 B
  __shared__ int lhist[NBK], lbase[NBK + 1], lcur[NBK], gbase[NBK];
  __shared__ int swsum[8];
  const int tid = threadIdx.x;
  const int bx = blockIdx.x;

  if (bx >= 512) {
    if (bx < 3637) {
      const int i = (bx - 512) * 512 + tid;
      const float4 v = *(const float4*)&h[(size_t)i * 4];
      half4 o = {(_Float16)v.x, (_Float16)v.y, (_Float16)v.z, (_Float16)v.w};
      *(half4*)&hh[(size_t)i * 4] = o;
    } else {
      const int L = (bx - 3637) * 512 + tid;
      const int g = L >> 14;          // layer 0..2
      const int idx = L & 16383;
      const float* bases = (g == 0) ? b0 : (g == 1) ? b1 : b2;
      const int o = idx >> 8, k = idx & 255;
      const int b = k >> 6, i = k & 63;
      bbt[g * 16384 + idx] = (_Float16)bases[b * 4096 + i * 64 + o];
    }
    return;
  }

  // ---- sort branch ----
  const int e0 = bx * CHUNK;

  if (tid < NBK) lhist[tid] = 0;
  __syncthreads();
  for (int i = tid; i < CHUNK; i += 512)
    atomicAdd(&lhist[dst[e0 + i] >> 8], 1);
  __syncthreads();
  {
    const int v = (tid < NBK) ? lhist[tid] : 0;
    int incl = v;
    for (int d = 1; d < 64; d <<= 1) {
      const int t = __shfl_up(incl, d);
      if ((tid & 63) >= d) incl += t;
    }
    if ((tid & 63) == 63) swsum[tid >> 6] = incl;
    __syncthreads();
    int pre = 0;
    for (int w = 0; w < (tid >> 6); ++w) pre += swsum[w];
    const int excl = pre + incl - v;
    if (tid < NBK) {
      lbase[tid] = excl;
      lcur[tid] = 0;
      gbase[tid] = tid * CAPB + atomicAdd(&gcur[tid], v);
    }
    if (tid == 0) lbase[NBK] = CHUNK;
  }
  __syncthreads();
  for (int i = tid; i < CHUNK; i += 512) {
    const int e = e0 + i;
    const int d = dst[e], s = src[e], et = etype[e];
    const _Float16 nh = (_Float16)norm[e];
    const unsigned short n16 = __builtin_bit_cast(unsigned short, nh);
    const int bk = d >> 8;
    const int pos = lbase[bk] + atomicAdd(&lcur[bk], 1);
    ldata[pos] = make_int2((d << 15) | (s >> 2), (s & 3) | (et << 2) | ((int)n16 << 5));
    lbkt[pos] = (unsigned short)bk;
  }
  __syncthreads();
  for (int i = tid; i < CHUNK; i += 512) {
    const int bk = (int)lbkt[i];
    part[gbase[bk] + (i - lbase[bk])] = ldata[i];
  }
}

// ---- pass B: per-bucket node histogram + scan -> off[]; exact placement ----
// 391 blocks x 1024 threads. Single-pass: records staged into LDS during
// the histogram read; placement reads LDS (wave-uniform two-pass fallback
// if a bucket exceeds LCAP = mean + 8 sigma).
// em record: x = (d&15)<<23 | et<<20 | src, y = norm fp32 bits.
__global__ __launch_bounds__(1024) void k_part2(const int* __restrict__ gcur,
                                                const int2* __restrict__ part,
                                                int* __restrict__ off,
                                                int2* __restrict__ em) {
  __shared__ int2 lrec[LCAP];   // 36864 B
  __shared__ int hcnt[256];
  __shared__ int wred[16];
  __shared__ int swsum[4];
  const int tid = threadIdx.x;
  const int bk = blockIdx.x;
  const int nb0 = bk << 8;
  const int2* __restrict__ pp = part + (size_t)bk * CAPB;

  {
    int pv = (tid < bk) ? gcur[tid] : 0;
    for (int d = 32; d > 0; d >>= 1) pv += __shfl_down(pv, d);
    if ((tid & 63) == 0) wred[tid >> 6] = pv;
  }
  if (tid < 256) hcnt[tid] = 0;
  __syncthreads();
  int base = 0;
#pragma unroll
  for (int w = 0; w < 16; ++w) base += wred[w];
  const int cntb = gcur[bk];
  const bool uselds = (cntb <= LCAP);

  if (uselds) {
    for (int i = tid; i < cntb; i += 1024) {
      const int2 r = pp[i];
      lrec[i] = r;
      atomicAdd(&hcnt[(((unsigned)r.x) >> 15) & 255], 1);
    }
  } else {
    for (int i = tid; i < cntb; i += 1024)
      atomicAdd(&hcnt[(((unsigned)pp[i].x) >> 15) & 255], 1);
  }
  __syncthreads();
  const int v = (tid < 256) ? hcnt[tid] : 0;
  int incl = v;
  for (int d = 1; d < 64; d <<= 1) {
    const int t = __shfl_up(incl, d);
    if ((tid & 63) >= d) incl += t;
  }
  if (tid < 256 && (tid & 63) == 63) swsum[tid >> 6] = incl;
  __syncthreads();
  if (tid < 256) {
    int pre = 0;
    for (int w = 0; w < (tid >> 6); ++w) pre += swsum[w];
    const int excl = pre + incl - v;  // bucket-local exclusive offset
    const int n = nb0 + tid;
    if (n < NN) off[n] = base + excl;
    hcnt[tid] = excl;  // cursors
  }
  if (bk == NBK - 1 && tid == 0) off[NN] = EE;
  __syncthreads();
  for (int i = tid; i < cntb; i += 1024) {
    const int2 r = uselds ? lrec[i] : pp[i];
    const int d = ((unsigned)r.x) >> 15;
    const int s = ((r.x & 0x7FFF) << 2) | (r.y & 3);
    const int et = (r.y >> 2) & 7;
    const unsigned short n16 = (unsigned short)((r.y >> 5) & 0xFFFF);
    const float nf = (float)__builtin_bit_cast(_Float16, n16);
    const int pos = atomicAdd(&hcnt[d & 255], 1);
    em[base + pos] = make_int2(((d & 15) << 23) | (et << 20) | s, __float_as_int(nf));
  }
}

// ---------------- fused layer: gather + basis-GEMM (MFMA) ----------------
// R9 core (54us, VGPR 32, no scratch; cvt_pkrtz staging) restructured to
// WAVE-PRIVATE staging: each wave zeros+stages only its own 4 nodes' LDS
// region (same-wave LDS RAW ordered by compiler lgkmcnt — no barrier);
// CSR offsets via lane<5 global loads + shfl (no offs LDS); wcomp read
// direct from L2/L1 (32 floats, hot); slow path decided per-wave. Only ONE
// block barrier remains (before MFMA, which reads other waves' Ash rows).
// Staging of wave k overlaps gathers of wave j.
// NOTE (R3+R5): deeper gather pipelines get stack-demoted by hipcc ->
// 500+MB scratch traffic. Do not re-attempt deep SWP at HIP source level.
__global__ __launch_bounds__(256, 8) void k_layer(const _Float16* __restrict__ hh,
                                                  const int* __restrict__ off,
                                                  const int2* __restrict__ em,
                                                  const float* __restrict__ wcomp,
                                                  const _Float16* __restrict__ bbt,
                                                  _Float16* __restrict__ out16,
                                                  float* __restrict__ out32) {
  __shared__ _Float16 Ash[16 * 264];   // 8448 B
  __shared__ int  ems_s[16 * NDCAP];   // 3072 B: src per slot
  __shared__ int2 ems_c[16 * NDCAP];   // 6144 B: coeff pairs {c0,c1},{c2,c3}
  const int tid = threadIdx.x;
  const int lane = tid & 63;
  const int wv = tid >> 6;
  const int n0 = blockIdx.x * 16;
  const int mb = wv * 4;

  // wave-private CSR offsets (lane<5 loads, broadcast via shfl)
  const int o_l = (lane < 5) ? off[n0 + mb + lane] : 0;
  const int oA = __shfl(o_l, 0), oB = __shfl(o_l, 1), oC = __shfl(o_l, 2),
            oD = __shfl(o_l, 3), oE = __shfl(o_l, 4);
  const int c0n = oB - oA, c1n = oC - oB, c2n = oD - oC, c3n = oE - oD;
  const bool wovf = (c0n > NDCAP) | (c1n > NDCAP) | (c2n > NDCAP) | (c3n > NDCAP);

  if (!wovf) {
    // wave-private zeroing of this wave's 4-node slot region
    int4* zs4 = (int4*)&ems_s[mb * NDCAP];   // 48 int4
    int4* zc4 = (int4*)&ems_c[mb * NDCAP];   // 96 int4
    const int4 z4 = make_int4(0, 0, 0, 0);
    if (lane < 48) zs4[lane] = z4;
    zc4[lane] = z4;
    if (lane < 32) zc4[64 + lane] = z4;
    // wave-private staging of em[oA, oE)
    const int len4 = oE - oA;
    for (int i = lane; i < len4; i += 64) {
      const int g = oA + i;
      const int2 r = em[g];
      const int lo = (r.x >> 23) & 15;       // block-local node idx (mb..mb+3)
      const int ob = ((lo & 3) == 0) ? oA : ((lo & 3) == 1) ? oB
                     : ((lo & 3) == 2) ? oC : oD;
      const int rank = g - ob;
      const int et = (r.x >> 20) & 7;
      const int s = r.x & 0xFFFFF;
      const float nf = __int_as_float(r.y);
      const float4 w = ((const float4*)wcomp)[et];
      const int p01i = __builtin_bit_cast(int, __builtin_amdgcn_cvt_pkrtz(nf * w.x, nf * w.y));
      const int p23i = __builtin_bit_cast(int, __builtin_amdgcn_cvt_pkrtz(nf * w.z, nf * w.w));
      ems_s[lo * NDCAP + rank] = s;
      ems_c[lo * NDCAP + rank] = make_int2(p01i, p23i);
    }
  }

#define LOADB(mm, bb, hv)                                                      \
  {                                                                            \
    const int4* sp4_ = (const int4*)&ems_s[(mm) * NDCAP + (bb) * 16 + eg * 8]; \
    const int4 sa_ = sp4_[0], sb_ = sp4_[1];                                   \
    hv[0] = hp[(unsigned)sa_.x * 32u + fl];                                    \
    hv[1] = hp[(unsigned)sa_.y * 32u + fl];                                    \
    hv[2] = hp[(unsigned)sa_.z * 32u + fl];                                    \
    hv[3] = hp[(unsigned)sa_.w * 32u + fl];                                    \
    hv[4] = hp[(unsigned)sb_.x * 32u + fl];                                    \
    hv[5] = hp[(unsigned)sb_.y * 32u + fl];                                    \
    hv[6] = hp[(unsigned)sb_.z * 32u + fl];                                    \
    hv[7] = hp[(unsigned)sb_.w * 32u + fl];                                    \
  }

#define FMAQ(mm, bb, hv, aq)                                                   \
  {                                                                            \
    const int4* cp4_ = (const int4*)&ems_c[(mm) * NDCAP + (bb) * 16 + eg * 8]; \
    _Pragma("unroll")                                                          \
    for (int k_ = 0; k_ < 4; ++k_) {                                           \
      const int4 c_ = cp4_[k_];                                                \
      const half2v pa01_ = __builtin_bit_cast(half2v, c_.x);                   \
      const half2v pa23_ = __builtin_bit_cast(half2v, c_.y);                   \
      const half2v pb01_ = __builtin_bit_cast(half2v, c_.z);                   \
      const half2v pb23_ = __builtin_bit_cast(half2v, c_.w);                   \
      aq[0] = aq[0] + hv[2 * k_] * __builtin_shufflevector(pa01_, pa01_, 0, 0);\
      aq[1] = aq[1] + hv[2 * k_] * __builtin_shufflevector(pa01_, pa01_, 1, 1);\
      aq[2] = aq[2] + hv[2 * k_] * __builtin_shufflevector(pa23_, pa23_, 0, 0);\
      aq[3] = aq[3] + hv[2 * k_] * __builtin_shufflevector(pa23_, pa23_, 1, 1);\
      aq[0] = aq[0] + hv[2 * k_ + 1] * __builtin_shufflevector(pb01_, pb01_, 0, 0);\
      aq[1] = aq[1] + hv[2 * k_ + 1] * __builtin_shufflevector(pb01_, pb01_, 1, 1);\
      aq[2] = aq[2] + hv[2 * k_ + 1] * __builtin_shufflevector(pb23_, pb23_, 0, 0);\
      aq[3] = aq[3] + hv[2 * k_ + 1] * __builtin_shufflevector(pb23_, pb23_, 1, 1);\
    }                                                                          \
  }

  if (!wovf) {
    // fast path: fp16 packed accumulation, zero-padded 16-slot batches,
    // depth-1 pipeline across the wave's 4 nodes (hvA/hvB double buffer).
    const int fl = lane & 31;   // feature pair index (feats 2fl, 2fl+1)
    const int eg = lane >> 5;   // edge group 0/1
    const half2v* __restrict__ hp = (const half2v*)hh;
    const int nb0_ = (c0n > 0) ? ((c0n + 15) >> 4) : 1;
    const int nb1_ = (c1n > 0) ? ((c1n + 15) >> 4) : 1;
    const int nb2_ = (c2n > 0) ? ((c2n + 15) >> 4) : 1;
    const int nb3_ = (c3n > 0) ? ((c3n + 15) >> 4) : 1;

    half2v acc[4][4];
#pragma unroll
    for (int q = 0; q < 4; ++q)
#pragma unroll
      for (int i = 0; i < 4; ++i) acc[q][i] = half2v{0, 0};

    half2v hvA[8], hvB[8];
    LOADB(mb, 0, hvA);
#pragma unroll
    for (int q = 0; q < 4; ++q) {
      const int m = mb + q;
      const int nbq = (q == 0) ? nb0_ : (q == 1) ? nb1_ : (q == 2) ? nb2_ : nb3_;
      if (q < 3) {
        if (q & 1) LOADB(m + 1, 0, hvA) else LOADB(m + 1, 0, hvB)
      }
      if (q & 1) FMAQ(m, 0, hvB, acc[q]) else FMAQ(m, 0, hvA, acc[q])
      for (int b = 1; b < nbq; ++b) {  // rare (deg > 16)
        if (q & 1) {
          LOADB(m, b, hvB) FMAQ(m, b, hvB, acc[q])
        } else {
          LOADB(m, b, hvA) FMAQ(m, b, hvA, acc[q])
        }
      }
    }
#pragma unroll
    for (int q = 0; q < 4; ++q) {
      const int m = mb + q;
#pragma unroll
      for (int i = 0; i < 4; ++i)
        acc[q][i] = acc[q][i] + __builtin_bit_cast(half2v,
            __shfl_xor(__builtin_bit_cast(int, acc[q][i]), 32));
      if (eg == 0) {
        _Float16* ar = &Ash[m * 264];
        *(half2v*)&ar[0 * 64 + 2 * fl] = acc[q][0];
        *(half2v*)&ar[1 * 64 + 2 * fl] = acc[q][1];
        *(half2v*)&ar[2 * 64 + 2 * fl] = acc[q][2];
        *(half2v*)&ar[3 * 64 + 2 * fl] = acc[q][3];
      }
    }
  } else {
    // slow path (deg > NDCAP): fp32 clamped batches straight from global em
    const _Float16* hl = hh + lane;
    const int pA[5] = {oA, oB, oC, oD, oE};
    for (int q = 0; q < 4; ++q) {
      const int m = mb + q;
      const int p0 = pA[q], p1 = pA[q + 1];
      float a0 = 0.f, a1 = 0.f, a2 = 0.f, a3 = 0.f;
      for (int p = p0; p < p1; p += 8) {
#pragma unroll
        for (int j = 0; j < 8; ++j) {
          const bool live = (p + j < p1);
          const int idx = live ? p + j : p1 - 1;
          const int2 mm = em[idx];
          const float hv = (float)hl[(size_t)(mm.x & 0xFFFFF) << 6];
          const float wn = live ? __int_as_float(mm.y) : 0.f;
          const float4 w = ((const float4*)wcomp)[(mm.x >> 20) & 7];
          const float t = wn * hv;
          a0 = fmaf(t, w.x, a0); a1 = fmaf(t, w.y, a1);
          a2 = fmaf(t, w.z, a2); a3 = fmaf(t, w.w, a3);
        }
      }
      _Float16* ar = &Ash[m * 264];
      ar[lane]       = (_Float16)a0;
      ar[64 + lane]  = (_Float16)a1;
      ar[128 + lane] = (_Float16)a2;
      ar[192 + lane] = (_Float16)a3;
    }
  }
  __syncthreads();

  // MFMA: C[16 nodes][16 outs] per wave, outs = wv*16..+15, K = 256.
  const int col = lane & 15;
  const int quad = lane >> 4;
  const int obase = wv * 16 + col;
  const _Float16* ap = &Ash[col * 264 + quad * 8];
  const _Float16* bp = &bbt[(size_t)obase * 256 + quad * 8];
  floatx4 acc2 = {0.f, 0.f, 0.f, 0.f};
#pragma unroll
  for (int s = 0; s < 8; ++s) {
    const half8 af = *(const half8*)(ap + s * 32);
    const half8 bf = *(const half8*)(bp + s * 32);
    acc2 = __builtin_amdgcn_mfma_f32_16x16x32_f16(af, bf, acc2, 0, 0, 0);
  }
  if (out16) {
#pragma unroll
    for (int r = 0; r < 4; ++r) {
      const float c = fmaxf(acc2[r], 0.f);
      out16[(size_t)(n0 + quad * 4 + r) * 64 + obase] = (_Float16)c;
    }
  } else {
#pragma unroll
    for (int r = 0; r < 4; ++r) {
      out32[(size_t)(n0 + quad * 4 + r) * 64 + obase] = acc2[r];
    }
  }
#undef LOADB
#undef FMAQ
}

// decoder: rec[n] = b2 + sum_o relu(b1[o] + henc[n,:]@w1[:,o]) * w2[o]
// grid 1024 (4 blocks/CU, 16 waves/CU).
__global__ __launch_bounds__(256) void k_dec(const float* __restrict__ henc,
                                             const float* __restrict__ w1,
                                             const float* __restrict__ b1,
                                             const float* __restrict__ w2,
                                             const float* __restrict__ b2,
                                             float* __restrict__ rec) {
  __shared__ float w1s[64 * 64];
  __shared__ float hs[16 * 68];
  const int tid = threadIdx.x;
  for (int r = tid; r < 1024; r += 256)
    *(float4*)&w1s[r * 4] = *(const float4*)&w1[r * 4];
  const int og = tid & 15;
  const int nl = tid >> 4;
  const float4 wv2 = *(const float4*)&w2[og * 4];
  const float4 bv1 = *(const float4*)&b1[og * 4];
  const float b2v = b2[0];
  for (int t0 = blockIdx.x * 16; t0 < NN; t0 += gridDim.x * 16) {
    __syncthreads();
    {
      const float4 hv = *(const float4*)&henc[(size_t)t0 * 64 + tid * 4];
      *(float4*)&hs[(tid >> 4) * 68 + (tid & 15) * 4] = hv;
    }
    __syncthreads();
    float4 acc = bv1;
    const float* hr = &hs[nl * 68];
#pragma unroll 8
    for (int i = 0; i < 64; ++i) {
      const float hv = hr[i];
      const float4 wv = *(const float4*)&w1s[i * 64 + og * 4];
      acc.x = fmaf(hv, wv.x, acc.x); acc.y = fmaf(hv, wv.y, acc.y);
      acc.z = fmaf(hv, wv.z, acc.z); acc.w = fmaf(hv, wv.w, acc.w);
    }
    acc.x = fmaxf(acc.x, 0.f); acc.y = fmaxf(acc.y, 0.f);
    acc.z = fmaxf(acc.z, 0.f); acc.w = fmaxf(acc.w, 0.f);
    float v = acc.x * wv2.x + acc.y * wv2.y + acc.z * wv2.z + acc.w * wv2.w;
    v += __shfl_xor(v, 1); v += __shfl_xor(v, 2);
    v += __shfl_xor(v, 4); v += __shfl_xor(v, 8);
    if (og == 0) rec[t0 + nl] = v + b2v;
  }
}

// ---------------- launch ----------------

extern "C" void kernel_launch(void* const* d_in, const int* in_sizes, int n_in,
                              void* d_out, int out_size, void* d_ws, size_t ws_size,
                              hipStream_t stream) {
  const float* h     = (const float*)d_in[0];
  const int*   src   = (const int*)d_in[1];
  const int*   dst   = (const int*)d_in[2];
  const int*   etype = (const int*)d_in[3];
  const float* norm  = (const float*)d_in[4];
  const float* bases[3] = {(const float*)d_in[5], (const float*)d_in[7], (const float*)d_in[9]};
  const float* wcomp[3] = {(const float*)d_in[6], (const float*)d_in[8], (const float*)d_in[10]};
  const float* dw1 = (const float*)d_in[11];
  const float* db1 = (const float*)d_in[12];
  const float* dw2 = (const float*)d_in[13];
  const float* db2 = (const float*)d_in[14];

  float* rec  = (float*)d_out;        // [N]
  float* henc = (float*)d_out + NN;   // [N,64] fp32 (layer-3 output)

  // workspace carve-up (16B-aligned)
  char* ws = (char*)d_ws;
  int*      off    = (int*)(ws + 0);              // (N+1) ints
  int*      gcur   = (int*)(ws + 400512);         // NBK bucket counters
  int2*     em     = (int2*)(ws + 402560);        // E records, dst-sorted
  _Float16* hh     = (_Float16*)(ws + 13202560);  // [N][64] fp16
  _Float16* h1f    = (_Float16*)(ws + 26002560);  // [N][64] fp16
  _Float16* h2f    = (_Float16*)(ws + 38802560);  // [N][64] fp16
  _Float16* bbt    = (_Float16*)(ws + 51602560);  // [3][64][256] fp16
  int2*     part   = (int2*)h1f;                  // NBK slabs x CAPB records
                                                  // (19.2 MB spanning h1f+h2f;
                                                  //  consumed in k_part2 before
                                                  //  layers write h1f/h2f)

  // ---- zero bucket counters (capture-safe async memset) ----
  hipMemsetAsync(gcur, 0, NBK * sizeof(int), stream);

  // ---- fused: dst-bucket sort (blocks 0-511) + fp16 prep (rest) ----
  k_partprep<<<3733, 512, 0, stream>>>(dst, src, etype, norm, gcur, part,
                                       h, hh, bases[0], bases[1], bases[2], bbt);
  k_part2<<<NBK, 1024, 0, stream>>>(gcur, part, off, em);

  // ---- fused layers ----
  k_layer<<<NN / 16, 256, 0, stream>>>(hh,  off, em, wcomp[0], bbt,         h1f, nullptr);
  k_layer<<<NN / 16, 256, 0, stream>>>(h1f, off, em, wcomp[1], bbt + 16384, h2f, nullptr);
  k_layer<<<NN / 16, 256, 0, stream>>>(h2f, off, em, wcomp[2], bbt + 32768, nullptr, henc);

  // ---- decoder ----
  k_dec<<<1024, 256, 0, stream>>>(henc, dw1, db1, dw2, db2, rec);
}

// Round 13
// 317.950 us; speedup vs baseline: 1.0624x; 1.0469x over previous
//
#include <hip/hip_runtime.h>

typedef _Float16 half8 __attribute__((ext_vector_type(8)));
typedef _Float16 half4 __attribute__((ext_vector_type(4)));
typedef _Float16 half2v __attribute__((ext_vector_type(2)));
typedef float floatx4 __attribute__((ext_vector_type(4)));

// Problem constants (fixed by reference)
constexpr int NN = 100000;   // nodes
constexpr int EE = 1600000;  // edges
constexpr int NBK = 391;     // partition buckets: ceil(100000/256), dst>>8
constexpr int CHUNK = 3125;  // edges per sort block (512 sort blocks)
constexpr int CAPB = 6144;   // per-bucket slab capacity (mean 4092, 32 sigma)
constexpr int LCAP = 4608;   // k_part2 LDS record capacity (mean + 8 sigma)
constexpr int NDCAP = 48;    // per-node LDS edge cap (mean deg 16; mult of 16)

// ---- fused pass A + prep ----
// Blocks [0,512): block-local counting sort into coarse buckets (dst>>8),
//   self-allocating slabs part[bk*CAPB...], gcur[bk] counts (zeroed by
//   hipMemsetAsync before launch).
// Blocks [512,3637): h fp32->fp16 conversion. Blocks [3637,3733): bbt.
// R7 lesson: no global-atomic hist/place (1.6M random atomics ~100+ us).
// R9 lesson: 1024 sort blocks regress (per-block overhead doubles).
// R11 lesson: dec-fusion into layer 3 costs +45us; keep k_dec standalone.
// R12 lesson: wave-private staging spills 16B/thread and gains nothing;
// keep the two-barrier block-wide staging structure.
// record: x = (dst<<15) | (src>>2); y = (src&3) | (et<<2) | (norm_fp16<<5)
__global__ __launch_bounds__(512) void k_partprep(const int* __restrict__ dst,
                                                  const int* __restrict__ src,
                                                  const int* __restrict__ etype,
                                                  const float* __restrict__ norm,
                                                  int* __restrict__ gcur,
                                                  int2* __restrict__ part,
                                                  const float* __restrict__ h,
                                                  _Float16* __restrict__ hh,
                                                  const float* __restrict__ b0,
                                                  const float* __restrict__ b1,
                                                  const float* __restrict__ b2,
                                                  _Float16* __restrict__ bbt) {
  __shared__ int2 ldata[CHUNK];             // 25000 B
  __shared__ unsigned short lbkt[CHUNK];    // 6250 B
  __shared__ int lhist[NBK], lbase[NBK + 1], lcur[NBK], gbase[NBK];
  __shared__ int swsum[8];
  const int tid = threadIdx.x;
  const int bx = blockIdx.x;

  if (bx >= 512) {
    if (bx < 3637) {
      const int i = (bx - 512) * 512 + tid;
      const float4 v = *(const float4*)&h[(size_t)i * 4];
      half4 o = {(_Float16)v.x, (_Float16)v.y, (_Float16)v.z, (_Float16)v.w};
      *(half4*)&hh[(size_t)i * 4] = o;
    } else {
      const int L = (bx - 3637) * 512 + tid;
      const int g = L >> 14;          // layer 0..2
      const int idx = L & 16383;
      const float* bases = (g == 0) ? b0 : (g == 1) ? b1 : b2;
      const int o = idx >> 8, k = idx & 255;
      const int b = k >> 6, i = k & 63;
      bbt[g * 16384 + idx] = (_Float16)bases[b * 4096 + i * 64 + o];
    }
    return;
  }

  // ---- sort branch ----
  const int e0 = bx * CHUNK;

  if (tid < NBK) lhist[tid] = 0;
  __syncthreads();
  for (int i = tid; i < CHUNK; i += 512)
    atomicAdd(&lhist[dst[e0 + i] >> 8], 1);
  __syncthreads();
  {
    const int v = (tid < NBK) ? lhist[tid] : 0;
    int incl = v;
    for (int d = 1; d < 64; d <<= 1) {
      const int t = __shfl_up(incl, d);
      if ((tid & 63) >= d) incl += t;
    }
    if ((tid & 63) == 63) swsum[tid >> 6] = incl;
    __syncthreads();
    int pre = 0;
    for (int w = 0; w < (tid >> 6); ++w) pre += swsum[w];
    const int excl = pre + incl - v;
    if (tid < NBK) {
      lbase[tid] = excl;
      lcur[tid] = 0;
      gbase[tid] = tid * CAPB + atomicAdd(&gcur[tid], v);
    }
    if (tid == 0) lbase[NBK] = CHUNK;
  }
  __syncthreads();
  for (int i = tid; i < CHUNK; i += 512) {
    const int e = e0 + i;
    const int d = dst[e], s = src[e], et = etype[e];
    const _Float16 nh = (_Float16)norm[e];
    const unsigned short n16 = __builtin_bit_cast(unsigned short, nh);
    const int bk = d >> 8;
    const int pos = lbase[bk] + atomicAdd(&lcur[bk], 1);
    ldata[pos] = make_int2((d << 15) | (s >> 2), (s & 3) | (et << 2) | ((int)n16 << 5));
    lbkt[pos] = (unsigned short)bk;
  }
  __syncthreads();
  for (int i = tid; i < CHUNK; i += 512) {
    const int bk = (int)lbkt[i];
    part[gbase[bk] + (i - lbase[bk])] = ldata[i];
  }
}

// ---- pass B: per-bucket node histogram + scan -> off[]; exact placement ----
// 391 blocks x 1024 threads. Single-pass: records staged into LDS during
// the histogram read; placement reads LDS (wave-uniform two-pass fallback
// if a bucket exceeds LCAP = mean + 8 sigma).
// em record: x = (d&15)<<23 | et<<20 | src, y = norm fp32 bits.
__global__ __launch_bounds__(1024) void k_part2(const int* __restrict__ gcur,
                                                const int2* __restrict__ part,
                                                int* __restrict__ off,
                                                int2* __restrict__ em) {
  __shared__ int2 lrec[LCAP];   // 36864 B
  __shared__ int hcnt[256];
  __shared__ int wred[16];
  __shared__ int swsum[4];
  const int tid = threadIdx.x;
  const int bk = blockIdx.x;
  const int nb0 = bk << 8;
  const int2* __restrict__ pp = part + (size_t)bk * CAPB;

  {
    int pv = (tid < bk) ? gcur[tid] : 0;
    for (int d = 32; d > 0; d >>= 1) pv += __shfl_down(pv, d);
    if ((tid & 63) == 0) wred[tid >> 6] = pv;
  }
  if (tid < 256) hcnt[tid] = 0;
  __syncthreads();
  int base = 0;
#pragma unroll
  for (int w = 0; w < 16; ++w) base += wred[w];
  const int cntb = gcur[bk];
  const bool uselds = (cntb <= LCAP);

  if (uselds) {
    for (int i = tid; i < cntb; i += 1024) {
      const int2 r = pp[i];
      lrec[i] = r;
      atomicAdd(&hcnt[(((unsigned)r.x) >> 15) & 255], 1);
    }
  } else {
    for (int i = tid; i < cntb; i += 1024)
      atomicAdd(&hcnt[(((unsigned)pp[i].x) >> 15) & 255], 1);
  }
  __syncthreads();
  const int v = (tid < 256) ? hcnt[tid] : 0;
  int incl = v;
  for (int d = 1; d < 64; d <<= 1) {
    const int t = __shfl_up(incl, d);
    if ((tid & 63) >= d) incl += t;
  }
  if (tid < 256 && (tid & 63) == 63) swsum[tid >> 6] = incl;
  __syncthreads();
  if (tid < 256) {
    int pre = 0;
    for (int w = 0; w < (tid >> 6); ++w) pre += swsum[w];
    const int excl = pre + incl - v;  // bucket-local exclusive offset
    const int n = nb0 + tid;
    if (n < NN) off[n] = base + excl;
    hcnt[tid] = excl;  // cursors
  }
  if (bk == NBK - 1 && tid == 0) off[NN] = EE;
  __syncthreads();
  for (int i = tid; i < cntb; i += 1024) {
    const int2 r = uselds ? lrec[i] : pp[i];
    const int d = ((unsigned)r.x) >> 15;
    const int s = ((r.x & 0x7FFF) << 2) | (r.y & 3);
    const int et = (r.y >> 2) & 7;
    const unsigned short n16 = (unsigned short)((r.y >> 5) & 0xFFFF);
    const float nf = (float)__builtin_bit_cast(_Float16, n16);
    const int pos = atomicAdd(&hcnt[d & 255], 1);
    em[base + pos] = make_int2(((d & 15) << 23) | (et << 20) | s, __float_as_int(nf));
  }
}

// ---------------- fused layer: gather + basis-GEMM (MFMA) ----------------
// R9/R10-proven version (54 us, VGPR 32, no scratch; cvt_pkrtz staging).
// Block = 16 dst nodes. Staging: node idx from em bits 23-26. Main loop:
// per wave 4 nodes, depth-1 software pipeline (double-buffered hvA/hvB),
// ds_read_b128 descriptor reads, zero-padded slots. 16x16 MFMA (K=256).
// NOTE (R3+R5): deeper pipelines get stack-demoted by hipcc -> 500+MB
// scratch traffic. (R12): wave-private staging spills; keep block-wide.
// k_layer is bound by random-gather memory throughput (~205MB/layer at
// ~3.7TB/s effective L3-random BW) — occupancy/ILP/issue levers are null.
__global__ __launch_bounds__(256, 8) void k_layer(const _Float16* __restrict__ hh,
                                                  const int* __restrict__ off,
                                                  const int2* __restrict__ em,
                                                  const float* __restrict__ wcomp,
                                                  const _Float16* __restrict__ bbt,
                                                  _Float16* __restrict__ out16,
                                                  float* __restrict__ out32) {
  __shared__ _Float16 Ash[16 * 264];   // 8448 B
  __shared__ int  ems_s[16 * NDCAP];   // 3072 B: src per slot
  __shared__ int2 ems_c[16 * NDCAP];   // 6144 B: coeff pairs {c0,c1},{c2,c3}
  __shared__ float4 wcs[8];
  __shared__ int offs[17];
  __shared__ int ovf;
  const int tid = threadIdx.x;
  const int lane = tid & 63;
  const int wv = tid >> 6;
  const int n0 = blockIdx.x * 16;

  if (tid < 17) offs[tid] = off[n0 + tid];
  if (tid == 0) ovf = 0;
  if (tid < 8) wcs[tid] = ((const float4*)wcomp)[tid];
  {
    const int4 z4 = make_int4(0, 0, 0, 0);
    int4* zs = (int4*)ems_s;  // 192 int4
    int4* zc = (int4*)ems_c;  // 384 int4
    if (tid < 192) zs[tid] = z4;
    for (int i = tid; i < 384; i += 256) zc[i] = z4;
  }
  __syncthreads();

  const int e0 = offs[0];
  const int len = offs[16] - e0;
  for (int i = tid; i < len; i += 256) {
    const int g = e0 + i;
    const int2 r = em[g];
    const int lo = (r.x >> 23) & 15;
    const int rank = g - offs[lo];
    const int et = (r.x >> 20) & 7;
    const int s = r.x & 0xFFFFF;
    const float nf = __int_as_float(r.y);
    const float4 w = wcs[et];
    const int p01i = __builtin_bit_cast(int, __builtin_amdgcn_cvt_pkrtz(nf * w.x, nf * w.y));
    const int p23i = __builtin_bit_cast(int, __builtin_amdgcn_cvt_pkrtz(nf * w.z, nf * w.w));
    if (rank < NDCAP) {
      ems_s[lo * NDCAP + rank] = s;
      ems_c[lo * NDCAP + rank] = make_int2(p01i, p23i);
    } else ovf = 1;
  }
  __syncthreads();

#define LOADB(mm, bb, hv)                                                      \
  {                                                                            \
    const int4* sp4_ = (const int4*)&ems_s[(mm) * NDCAP + (bb) * 16 + eg * 8]; \
    const int4 sa_ = sp4_[0], sb_ = sp4_[1];                                   \
    hv[0] = hp[(unsigned)sa_.x * 32u + fl];                                    \
    hv[1] = hp[(unsigned)sa_.y * 32u + fl];                                    \
    hv[2] = hp[(unsigned)sa_.z * 32u + fl];                                    \
    hv[3] = hp[(unsigned)sa_.w * 32u + fl];                                    \
    hv[4] = hp[(unsigned)sb_.x * 32u + fl];                                    \
    hv[5] = hp[(unsigned)sb_.y * 32u + fl];                                    \
    hv[6] = hp[(unsigned)sb_.z * 32u + fl];                                    \
    hv[7] = hp[(unsigned)sb_.w * 32u + fl];                                    \
  }

#define FMAQ(mm, bb, hv, aq)                                                   \
  {                                                                            \
    const int4* cp4_ = (const int4*)&ems_c[(mm) * NDCAP + (bb) * 16 + eg * 8]; \
    _Pragma("unroll")                                                          \
    for (int k_ = 0; k_ < 4; ++k_) {                                           \
      const int4 c_ = cp4_[k_];                                                \
      const half2v pa01_ = __builtin_bit_cast(half2v, c_.x);                   \
      const half2v pa23_ = __builtin_bit_cast(half2v, c_.y);                   \
      const half2v pb01_ = __builtin_bit_cast(half2v, c_.z);                   \
      const half2v pb23_ = __builtin_bit_cast(half2v, c_.w);                   \
      aq[0] = aq[0] + hv[2 * k_] * __builtin_shufflevector(pa01_, pa01_, 0, 0);\
      aq[1] = aq[1] + hv[2 * k_] * __builtin_shufflevector(pa01_, pa01_, 1, 1);\
      aq[2] = aq[2] + hv[2 * k_] * __builtin_shufflevector(pa23_, pa23_, 0, 0);\
      aq[3] = aq[3] + hv[2 * k_] * __builtin_shufflevector(pa23_, pa23_, 1, 1);\
      aq[0] = aq[0] + hv[2 * k_ + 1] * __builtin_shufflevector(pb01_, pb01_, 0, 0);\
      aq[1] = aq[1] + hv[2 * k_ + 1] * __builtin_shufflevector(pb01_, pb01_, 1, 1);\
      aq[2] = aq[2] + hv[2 * k_ + 1] * __builtin_shufflevector(pb23_, pb23_, 0, 0);\
      aq[3] = aq[3] + hv[2 * k_ + 1] * __builtin_shufflevector(pb23_, pb23_, 1, 1);\
    }                                                                          \
  }

  if (!ovf) {
    // fast path: fp16 packed accumulation, zero-padded 16-slot batches,
    // depth-1 pipeline across the wave's 4 nodes (hvA/hvB double buffer).
    const int fl = lane & 31;   // feature pair index (feats 2fl, 2fl+1)
    const int eg = lane >> 5;   // edge group 0/1
    const half2v* __restrict__ hp = (const half2v*)hh;
    const int mb = wv * 4;
    const int oA = offs[mb], oB = offs[mb + 1], oC = offs[mb + 2],
              oD = offs[mb + 3], oE = offs[mb + 4];
    const int c0n = oB - oA, c1n = oC - oB, c2n = oD - oC, c3n = oE - oD;
    const int nb0_ = (c0n > 0) ? ((c0n + 15) >> 4) : 1;
    const int nb1_ = (c1n > 0) ? ((c1n + 15) >> 4) : 1;
    const int nb2_ = (c2n > 0) ? ((c2n + 15) >> 4) : 1;
    const int nb3_ = (c3n > 0) ? ((c3n + 15) >> 4) : 1;

    half2v acc[4][4];
#pragma unroll
    for (int q = 0; q < 4; ++q)
#pragma unroll
      for (int i = 0; i < 4; ++i) acc[q][i] = half2v{0, 0};

    half2v hvA[8], hvB[8];
    LOADB(mb, 0, hvA);
#pragma unroll
    for (int q = 0; q < 4; ++q) {
      const int m = mb + q;
      const int nbq = (q == 0) ? nb0_ : (q == 1) ? nb1_ : (q == 2) ? nb2_ : nb3_;
      if (q < 3) {
        if (q & 1) LOADB(m + 1, 0, hvA) else LOADB(m + 1, 0, hvB)
      }
      if (q & 1) FMAQ(m, 0, hvB, acc[q]) else FMAQ(m, 0, hvA, acc[q])
      for (int b = 1; b < nbq; ++b) {  // rare (deg > 16)
        if (q & 1) {
          LOADB(m, b, hvB) FMAQ(m, b, hvB, acc[q])
        } else {
          LOADB(m, b, hvA) FMAQ(m, b, hvA, acc[q])
        }
      }
    }
#pragma unroll
    for (int q = 0; q < 4; ++q) {
      const int m = mb + q;
#pragma unroll
      for (int i = 0; i < 4; ++i)
        acc[q][i] = acc[q][i] + __builtin_bit_cast(half2v,
            __shfl_xor(__builtin_bit_cast(int, acc[q][i]), 32));
      if (eg == 0) {
        _Float16* ar = &Ash[m * 264];
        *(half2v*)&ar[0 * 64 + 2 * fl] = acc[q][0];
        *(half2v*)&ar[1 * 64 + 2 * fl] = acc[q][1];
        *(half2v*)&ar[2 * 64 + 2 * fl] = acc[q][2];
        *(half2v*)&ar[3 * 64 + 2 * fl] = acc[q][3];
      }
    }
  } else {
    // slow path (deg > NDCAP): fp32 clamped batches straight from global em
    const _Float16* hl = hh + lane;
    for (int q = 0; q < 4; ++q) {
      const int m = wv * 4 + q;
      const int p0 = offs[m], p1 = offs[m + 1];
      float a0 = 0.f, a1 = 0.f, a2 = 0.f, a3 = 0.f;
      for (int p = p0; p < p1; p += 8) {
#pragma unroll
        for (int j = 0; j < 8; ++j) {
          const bool live = (p + j < p1);
          const int idx = live ? p + j : p1 - 1;
          const int2 mm = em[idx];
          const float hv = (float)hl[(size_t)(mm.x & 0xFFFFF) << 6];
          const float wn = live ? __int_as_float(mm.y) : 0.f;
          const float4 w = wcs[(mm.x >> 20) & 7];
          const float t = wn * hv;
          a0 = fmaf(t, w.x, a0); a1 = fmaf(t, w.y, a1);
          a2 = fmaf(t, w.z, a2); a3 = fmaf(t, w.w, a3);
        }
      }
      _Float16* ar = &Ash[m * 264];
      ar[lane]       = (_Float16)a0;
      ar[64 + lane]  = (_Float16)a1;
      ar[128 + lane] = (_Float16)a2;
      ar[192 + lane] = (_Float16)a3;
    }
  }
  __syncthreads();

  // MFMA: C[16 nodes][16 outs] per wave, outs = wv*16..+15, K = 256.
  const int col = lane & 15;
  const int quad = lane >> 4;
  const int obase = wv * 16 + col;
  const _Float16* ap = &Ash[col * 264 + quad * 8];
  const _Float16* bp = &bbt[(size_t)obase * 256 + quad * 8];
  floatx4 acc2 = {0.f, 0.f, 0.f, 0.f};
#pragma unroll
  for (int s = 0; s < 8; ++s) {
    const half8 af = *(const half8*)(ap + s * 32);
    const half8 bf = *(const half8*)(bp + s * 32);
    acc2 = __builtin_amdgcn_mfma_f32_16x16x32_f16(af, bf, acc2, 0, 0, 0);
  }
  if (out16) {
#pragma unroll
    for (int r = 0; r < 4; ++r) {
      const float c = fmaxf(acc2[r], 0.f);
      out16[(size_t)(n0 + quad * 4 + r) * 64 + obase] = (_Float16)c;
    }
  } else {
#pragma unroll
    for (int r = 0; r < 4; ++r) {
      out32[(size_t)(n0 + quad * 4 + r) * 64 + obase] = acc2[r];
    }
  }
#undef LOADB
#undef FMAQ
}

// decoder: rec[n] = b2 + sum_o relu(b1[o] + henc[n,:]@w1[:,o]) * w2[o]
// grid 1024 (4 blocks/CU, 16 waves/CU).
__global__ __launch_bounds__(256) void k_dec(const float* __restrict__ henc,
                                             const float* __restrict__ w1,
                                             const float* __restrict__ b1,
                                             const float* __restrict__ w2,
                                             const float* __restrict__ b2,
                                             float* __restrict__ rec) {
  __shared__ float w1s[64 * 64];
  __shared__ float hs[16 * 68];
  const int tid = threadIdx.x;
  for (int r = tid; r < 1024; r += 256)
    *(float4*)&w1s[r * 4] = *(const float4*)&w1[r * 4];
  const int og = tid & 15;
  const int nl = tid >> 4;
  const float4 wv2 = *(const float4*)&w2[og * 4];
  const float4 bv1 = *(const float4*)&b1[og * 4];
  const float b2v = b2[0];
  for (int t0 = blockIdx.x * 16; t0 < NN; t0 += gridDim.x * 16) {
    __syncthreads();
    {
      const float4 hv = *(const float4*)&henc[(size_t)t0 * 64 + tid * 4];
      *(float4*)&hs[(tid >> 4) * 68 + (tid & 15) * 4] = hv;
    }
    __syncthreads();
    float4 acc = bv1;
    const float* hr = &hs[nl * 68];
#pragma unroll 8
    for (int i = 0; i < 64; ++i) {
      const float hv = hr[i];
      const float4 wv = *(const float4*)&w1s[i * 64 + og * 4];
      acc.x = fmaf(hv, wv.x, acc.x); acc.y = fmaf(hv, wv.y, acc.y);
      acc.z = fmaf(hv, wv.z, acc.z); acc.w = fmaf(hv, wv.w, acc.w);
    }
    acc.x = fmaxf(acc.x, 0.f); acc.y = fmaxf(acc.y, 0.f);
    acc.z = fmaxf(acc.z, 0.f); acc.w = fmaxf(acc.w, 0.f);
    float v = acc.x * wv2.x + acc.y * wv2.y + acc.z * wv2.z + acc.w * wv2.w;
    v += __shfl_xor(v, 1); v += __shfl_xor(v, 2);
    v += __shfl_xor(v, 4); v += __shfl_xor(v, 8);
    if (og == 0) rec[t0 + nl] = v + b2v;
  }
}

// ---------------- launch ----------------

extern "C" void kernel_launch(void* const* d_in, const int* in_sizes, int n_in,
                              void* d_out, int out_size, void* d_ws, size_t ws_size,
                              hipStream_t stream) {
  const float* h     = (const float*)d_in[0];
  const int*   src   = (const int*)d_in[1];
  const int*   dst   = (const int*)d_in[2];
  const int*   etype = (const int*)d_in[3];
  const float* norm  = (const float*)d_in[4];
  const float* bases[3] = {(const float*)d_in[5], (const float*)d_in[7], (const float*)d_in[9]};
  const float* wcomp[3] = {(const float*)d_in[6], (const float*)d_in[8], (const float*)d_in[10]};
  const float* dw1 = (const float*)d_in[11];
  const float* db1 = (const float*)d_in[12];
  const float* dw2 = (const float*)d_in[13];
  const float* db2 = (const float*)d_in[14];

  float* rec  = (float*)d_out;        // [N]
  float* henc = (float*)d_out + NN;   // [N,64] fp32 (layer-3 output)

  // workspace carve-up (16B-aligned)
  char* ws = (char*)d_ws;
  int*      off    = (int*)(ws + 0);              // (N+1) ints
  int*      gcur   = (int*)(ws + 400512);         // NBK bucket counters
  int2*     em     = (int2*)(ws + 402560);        // E records, dst-sorted
  _Float16* hh     = (_Float16*)(ws + 13202560);  // [N][64] fp16
  _Float16* h1f    = (_Float16*)(ws + 26002560);  // [N][64] fp16
  _Float16* h2f    = (_Float16*)(ws + 38802560);  // [N][64] fp16
  _Float16* bbt    = (_Float16*)(ws + 51602560);  // [3][64][256] fp16
  int2*     part   = (int2*)h1f;                  // NBK slabs x CAPB records
                                                  // (19.2 MB spanning h1f+h2f;
                                                  //  consumed in k_part2 before
                                                  //  layers write h1f/h2f)

  // ---- zero bucket counters (capture-safe async memset) ----
  hipMemsetAsync(gcur, 0, NBK * sizeof(int), stream);

  // ---- fused: dst-bucket sort (blocks 0-511) + fp16 prep (rest) ----
  k_partprep<<<3733, 512, 0, stream>>>(dst, src, etype, norm, gcur, part,
                                       h, hh, bases[0], bases[1], bases[2], bbt);
  k_part2<<<NBK, 1024, 0, stream>>>(gcur, part, off, em);

  // ---- fused layers ----
  k_layer<<<NN / 16, 256, 0, stream>>>(hh,  off, em, wcomp[0], bbt,         h1f, nullptr);
  k_layer<<<NN / 16, 256, 0, stream>>>(h1f, off, em, wcomp[1], bbt + 16384, h2f, nullptr);
  k_layer<<<NN / 16, 256, 0, stream>>>(h2f, off, em, wcomp[2], bbt + 32768, nullptr, henc);

  // ---- decoder ----
  k_dec<<<1024, 256, 0, stream>>>(henc, dw1, db1, dw2, db2, rec);
}